// Round 9
// baseline (351.288 us; speedup 1.0000x reference)
//
#include <hip/hip_runtime.h>
#include <math.h>

#define NUM_HEADS 12
#define HEAD_DIM  64
#define HIDDEN    768
#define BS        8
#define FULL      240
#define SLOT_LEN  32
#define LEN0      512
#define LEN1      128
#define KTOT      672
#define M_TOK     (FULL * SLOT_LEN)   // 7680

#define HS_SHORTS   ((size_t)M_TOK * HIDDEN)                        // 5,898,240
#define WT_SHORTS   ((size_t)3 * HIDDEN * HIDDEN)                   // 1,769,472
#define QKV_SHORTS  ((size_t)M_TOK * HIDDEN)                        // each of q/k/v
#define C0_SHORTS   ((size_t)BS * NUM_HEADS * LEN0 * HEAD_DIM)      // 3,145,728

#define HS_BLOCKS   5760    // M_TOK*HIDDEN/4/256
#define W_BLOCKS    1728    // 3*24*24
#define C0K_BLOCKS  3072    // C0_SHORTS/4/256
#define C0V_BLOCKS  1536    // C0_SHORTS/2048 chunks (R8 bug: was 192 -> 87.5% of v0f garbage)
#define C0_BLOCKS   (C0K_BLOCKS + C0V_BLOCKS)

typedef float f32x4 __attribute__((ext_vector_type(4)));
typedef short s16x8 __attribute__((ext_vector_type(8)));
typedef short s16x4 __attribute__((ext_vector_type(4)));

__device__ __forceinline__ short f2bf(float x) {
    unsigned u = __float_as_uint(x);
    unsigned r = (u + 0x7fffu + ((u >> 16) & 1u)) >> 16;
    return (short)r;
}

// async global->LDS, 16B per lane; lds base must be wave-uniform
__device__ __forceinline__ void gll16(const short* g, short* l) {
    __builtin_amdgcn_global_load_lds(
        (const __attribute__((address_space(1))) unsigned int*)g,
        (__attribute__((address_space(3))) unsigned int*)l, 16, 0, 0);
}

// ---------------------------------------------------------------------------
// prep_all: block-range-dispatched fusion of three independent pre-passes.
//   [0, hsB):            bf16 cast of hidden_states (flat float4)
//   [hsB, hsB+wB):       W^T bf16 cast (3 x 768x768, 32x32 LDS transpose)
//   [hsB+wB, ...):       cache0 prep: first C0K_BLOCKS flat-cast K0,
//                        next C0V_BLOCKS frag-major transpose V0.
// ---------------------------------------------------------------------------
__global__ __launch_bounds__(256) void prep_all(
    const float* __restrict__ hs, const float* __restrict__ Wq,
    const float* __restrict__ Wk, const float* __restrict__ Wv,
    const float* __restrict__ k0, const float* __restrict__ v0,
    short* __restrict__ hsb, short* __restrict__ WtAll,
    short* __restrict__ k0c, short* __restrict__ v0f,
    int hsB, int wB)
{
    __shared__ __align__(16) float tile[32][65];
    const int t = threadIdx.x;
    const int b = blockIdx.x;

    if (b < hsB) {                                    // ---- cast_hs
        int i = b * 256 + t;
        float4 v = ((const float4*)hs)[i];
        s16x4 o = {f2bf(v.x), f2bf(v.y), f2bf(v.z), f2bf(v.w)};
        ((s16x4*)hsb)[i] = o;
        return;
    }
    if (b < hsB + wB) {                               // ---- cast_w_t
        int wb = b - hsB;
        int z = wb / 576, rem = wb % 576, by = rem / 24, bx = rem % 24;
        const float* W = (z == 0) ? Wq : (z == 1) ? Wk : Wv;
        short* Wt = WtAll + (size_t)z * HIDDEN * HIDDEN;
        const int kb0 = by * 32, nb0 = bx * 32;
        const int r = t >> 3, c4 = (t & 7) * 4;
        float4 v = *(const float4*)&W[(size_t)(kb0 + r) * HIDDEN + nb0 + c4];
        tile[r][c4 + 0] = v.x; tile[r][c4 + 1] = v.y;
        tile[r][c4 + 2] = v.z; tile[r][c4 + 3] = v.w;
        __syncthreads();
        s16x4 o = {f2bf(tile[c4 + 0][r]), f2bf(tile[c4 + 1][r]),
                   f2bf(tile[c4 + 2][r]), f2bf(tile[c4 + 3][r])};
        *(s16x4*)&Wt[(size_t)(nb0 + r) * HIDDEN + kb0 + c4] = o;
        return;
    }
    int cb = b - hsB - wB;                            // ---- cache0 prep
    if (cb < C0K_BLOCKS) {                            // flat-cast K0
        int i = cb * 256 + t;
        float4 v = ((const float4*)k0)[i];
        s16x4 o = {f2bf(v.x), f2bf(v.y), f2bf(v.z), f2bf(v.w)};
        ((s16x4*)k0c)[i] = o;
        return;
    }
    // frag-major transpose of V0: one block per 32-key chunk
    const size_t base = (size_t)(cb - C0K_BLOCKS) * 2048;
#pragma unroll
    for (int i = 0; i < 2; ++i) {
        int f = t + i * 256;                          // float4 unit, 512 total
        int kr = f >> 4, d4 = (f & 15) * 4;
        float4 v = *(const float4*)&v0[base + kr * 64 + d4];
        tile[kr][d4 + 0] = v.x; tile[kr][d4 + 1] = v.y;
        tile[kr][d4 + 2] = v.z; tile[kr][d4 + 3] = v.w;
    }
    __syncthreads();
    const int dq = t >> 6, lane = t & 63;
    const int quad = lane >> 4, l15 = lane & 15;
    s16x8 o = {f2bf(tile[quad * 8 + 0][dq * 16 + l15]),
               f2bf(tile[quad * 8 + 1][dq * 16 + l15]),
               f2bf(tile[quad * 8 + 2][dq * 16 + l15]),
               f2bf(tile[quad * 8 + 3][dq * 16 + l15]),
               f2bf(tile[quad * 8 + 4][dq * 16 + l15]),
               f2bf(tile[quad * 8 + 5][dq * 16 + l15]),
               f2bf(tile[quad * 8 + 6][dq * 16 + l15]),
               f2bf(tile[quad * 8 + 7][dq * 16 + l15])};
    *(s16x8*)&v0f[base + (size_t)t * 8] = o;
}

// ---------------------------------------------------------------------------
// QKV GEMM: 128x128 tile, BK=64, global_load_lds(16B) staging, XOR-swizzled
// unpadded LDS. Epilogue: z==0 (Q) and z==1 (K) write row-major [B,h][key][d];
// z==2 (V) writes FRAG-MAJOR per (B,h) via a transposed smem pass.
// ---------------------------------------------------------------------------
__global__ __launch_bounds__(256) void qkv_mfma(
    const short* __restrict__ hsb, const short* __restrict__ WtAll,
    const float* __restrict__ bq, const float* __restrict__ bk,
    const float* __restrict__ bv,
    short* __restrict__ qo, short* __restrict__ ko, short* __restrict__ vo)
{
    const int z = blockIdx.z;
    const short* Wt = WtAll + (size_t)z * HIDDEN * HIDDEN;
    const float* bias = (z == 0) ? bq : (z == 1) ? bk : bv;
    short* outp = (z == 0) ? qo : (z == 1) ? ko : vo;

    __shared__ __align__(16) short smem[128 * 144];   // 36.9KB; K-loop uses first 32KB
    short* As = smem;
    short* Bs = smem + 128 * 64;

    const int t = threadIdx.x;
    const int lane = t & 63, w = t >> 6;
    const int l15 = lane & 15, quad = lane >> 4;
    const int mBase = blockIdx.y * 128, nBase = blockIdx.x * 128;
    const int mw = (w & 1) * 64, nw = (w >> 1) * 64;

    const int srow_in = lane >> 3;
    const int scol8 = (lane & 7) ^ srow_in;

    f32x4 acc[4][4];
    const f32x4 z4 = {0.f, 0.f, 0.f, 0.f};
#pragma unroll
    for (int i = 0; i < 4; ++i)
#pragma unroll
        for (int j = 0; j < 4; ++j) acc[i][j] = z4;

    for (int kb = 0; kb < HIDDEN; kb += 64) {
        __syncthreads();
#pragma unroll
        for (int j = 0; j < 4; ++j) {
            int row = w * 32 + j * 8 + srow_in;
            gll16(&hsb[(size_t)(mBase + row) * HIDDEN + kb + scol8 * 8],
                  &As[(w * 32 + j * 8) * 64]);
            gll16(&Wt[(size_t)(nBase + row) * HIDDEN + kb + scol8 * 8],
                  &Bs[(w * 32 + j * 8) * 64]);
        }
        __syncthreads();
#pragma unroll
        for (int kc = 0; kc < 2; ++kc) {
            s16x8 a[4], b[4];
#pragma unroll
            for (int mt = 0; mt < 4; ++mt) {
                int row = mw + mt * 16 + l15;
                int c8 = (kc * 4 + quad) ^ (row & 7);
                a[mt] = *(const s16x8*)&As[row * 64 + c8 * 8];
            }
#pragma unroll
            for (int nt = 0; nt < 4; ++nt) {
                int row = nw + nt * 16 + l15;
                int c8 = (kc * 4 + quad) ^ (row & 7);
                b[nt] = *(const s16x8*)&Bs[row * 64 + c8 * 8];
            }
#pragma unroll
            for (int mt = 0; mt < 4; ++mt)
#pragma unroll
                for (int nt = 0; nt < 4; ++nt)
                    acc[mt][nt] = __builtin_amdgcn_mfma_f32_16x16x32_bf16(
                        a[mt], b[nt], acc[mt][nt], 0, 0, 0);
        }
    }

    __syncthreads();
#pragma unroll
    for (int nt = 0; nt < 4; ++nt) {
        float bvv = bias[nBase + nw + nt * 16 + l15];
        int col = nw + nt * 16 + l15;
#pragma unroll
        for (int mt = 0; mt < 4; ++mt)
#pragma unroll
            for (int r = 0; r < 4; ++r) {
                int row = mw + mt * 16 + quad * 4 + r;
                short v = f2bf(acc[mt][nt][r] + bvv);
                if (z == 2) smem[col * 144 + row] = v;     // transposed for frag-major store
                else        smem[row * 128 + col] = v;
            }
    }
    __syncthreads();
    if (z == 2) {
#pragma unroll
        for (int i = 0; i < 8; ++i) {
            int f = t + i * 256;
            int d = f >> 4, kb8 = (f & 15) * 8;            // n-local d, 8-key group
            uint4 val = *(const uint4*)&smem[d * 144 + kb8];
            int m0 = mBase + kb8, n = nBase + d;
            int B = m0 >> 5, key0 = m0 & 31, hh = n >> 6, dd = n & 63;
            size_t dst = ((size_t)(B * NUM_HEADS + hh) * 2048) +
                         (size_t)((dd >> 4) * 512 + (key0 >> 3) * 128 + (dd & 15) * 8);
            *(uint4*)&outp[dst] = val;
        }
    } else {
#pragma unroll
        for (int i = 0; i < 8; ++i) {
            int f = t + i * 256;
            int row = f >> 4, c8 = (f & 15) * 8;
            uint4 val = *(const uint4*)&smem[row * 128 + c8];
            int m = mBase + row, n = nBase + c8;
            size_t dst = (((size_t)(m >> 5) * NUM_HEADS + (n >> 6)) * SLOT_LEN + (m & 31)) * 64 + (n & 63);
            *(uint4*)&outp[dst] = val;
        }
    }
}

// ---------------------------------------------------------------------------
// Attention v5 + setprio: ONE BLOCK per (B,h); 4 waves split 21 chunks.
// Frag-direct K/V, 2-deep A/B register prefetch (R7 structure, 93 us).
// s_setprio(1) around MFMA clusters (T5) - waves are barrier-free and
// phase-independent here, the regime where it measured +4-7% (m191).
// ---------------------------------------------------------------------------
__global__ __launch_bounds__(256) void attn_mfma(
    const short* __restrict__ qb, const short* __restrict__ kbuf,
    const short* __restrict__ vbuf,
    const short* __restrict__ k0c, const short* __restrict__ v0f,
    const float* __restrict__ c1k, const float* __restrict__ c1v,
    const float* __restrict__ mask, float* __restrict__ out)
{
    __shared__ __align__(16) float smf[8448];     // 33792 B, aliased below
    short* sm16 = (short*)smf;

    const int t = threadIdx.x, lane = t & 63, w = t >> 6;
    const int task = blockIdx.x;                  // < 2880
    const int B = task / 12, h = task % 12;
    const int l15 = lane & 15, quad = lane >> 4;

    const short* qp   = qb  + (size_t)(B * NUM_HEADS + h) * 2048;
    const short* kspF = kbuf + (size_t)(B * NUM_HEADS + h) * 2048;   // row-major
    const short* vspF = vbuf + (size_t)(B * NUM_HEADS + h) * 2048;   // frag-major
    const short* k0p  = k0c + (size_t)((B & 7) * NUM_HEADS + h) * LEN0 * 64;  // row-major
    const short* v0p  = v0f + (size_t)((B & 7) * NUM_HEADS + h) * LEN0 * 64;  // frag-major
    const float* k1p  = c1k + (size_t)(B * NUM_HEADS + h) * LEN1 * 64;
    const float* v1p  = c1v + (size_t)(B * NUM_HEADS + h) * LEN1 * 64;
    const float* mp   = mask + (size_t)B * KTOT;

    short (*V)[32] = (short(*)[32])(sm16 + w * 3072);          // cache1 V staging
    short (*P)[32] = (short(*)[32])(sm16 + w * 3072 + 2048);

    const int skey = lane >> 4;               // f32 V staging: lane -> (key%4, c4)
    const int sc4 = (lane & 15) << 2;

    const float LOG2E = 1.4426950408889634f;
    const float SCL   = 0.125f * 1.4426950408889634f;

    // Q fragments
    s16x8 qf[2][2];
#pragma unroll
    for (int qh = 0; qh < 2; ++qh)
#pragma unroll
        for (int kc = 0; kc < 2; ++kc)
            qf[qh][kc] = *(const s16x8*)&qp[(qh * 16 + l15) * 64 + kc * 32 + quad * 8];

    const f32x4 z4 = {0.f, 0.f, 0.f, 0.f};
    f32x4 o[2][4];
    float lpart[2][4];
#pragma unroll
    for (int qh = 0; qh < 2; ++qh) {
#pragma unroll
        for (int dq = 0; dq < 4; ++dq) o[qh][dq] = z4;
#pragma unroll
        for (int r = 0; r < 4; ++r) lpart[qh][r] = 0.f;
    }

    // ---- compute pieces ---------------------------------------------------
    auto qk_mm = [&](const s16x8* kf, f32x4 (*s)[2]) {
#pragma unroll
        for (int qh = 0; qh < 2; ++qh)
#pragma unroll
            for (int kh = 0; kh < 2; ++kh) s[qh][kh] = z4;
        __builtin_amdgcn_s_setprio(1);
#pragma unroll
        for (int kh = 0; kh < 2; ++kh)
#pragma unroll
            for (int qh = 0; qh < 2; ++qh) {
                s[qh][kh] = __builtin_amdgcn_mfma_f32_16x16x32_bf16(qf[qh][0], kf[kh * 2 + 0], s[qh][kh], 0, 0, 0);
                s[qh][kh] = __builtin_amdgcn_mfma_f32_16x16x32_bf16(qf[qh][1], kf[kh * 2 + 1], s[qh][kh], 0, 0, 0);
            }
        __builtin_amdgcn_s_setprio(0);
    };
    auto exp_p = [&](f32x4 (*s)[2], float mv0, float mv1) {
#pragma unroll
        for (int qh = 0; qh < 2; ++qh)
#pragma unroll
            for (int kh = 0; kh < 2; ++kh) {
                float mv = kh ? mv1 : mv0;
#pragma unroll
                for (int r = 0; r < 4; ++r) {
                    float p = exp2f(fmaf(s[qh][kh][r], SCL, mv));
                    lpart[qh][r] += p;
                    int prow = qh * 16 + quad * 4 + r;
                    int pswz = ((kh * 2 + (l15 >> 3)) ^ ((prow >> 1) & 3)) * 8 + (l15 & 7);
                    P[prow][pswz] = f2bf(p);
                }
            }
    };
    auto pv_reg = [&](const s16x8* vf) {
#pragma unroll
        for (int qh = 0; qh < 2; ++qh) {
            int prow2 = qh * 16 + l15;
            int pg = (quad ^ ((l15 >> 1) & 3)) * 8;
            s16x4 plo = *(const s16x4*)&P[prow2][pg];
            s16x4 phi = *(const s16x4*)&P[prow2][pg + 4];
            s16x8 pf = __builtin_shufflevector(plo, phi, 0, 1, 2, 3, 4, 5, 6, 7);
            __builtin_amdgcn_s_setprio(1);
#pragma unroll
            for (int dq = 0; dq < 4; ++dq)
                o[qh][dq] = __builtin_amdgcn_mfma_f32_16x16x32_bf16(pf, vf[dq], o[qh][dq], 0, 0, 0);
            __builtin_amdgcn_s_setprio(0);
        }
    };
    auto pv_lds = [&]() {
#pragma unroll
        for (int qh = 0; qh < 2; ++qh) {
            int prow2 = qh * 16 + l15;
            int pg = (quad ^ ((l15 >> 1) & 3)) * 8;
            s16x4 plo = *(const s16x4*)&P[prow2][pg];
            s16x4 phi = *(const s16x4*)&P[prow2][pg + 4];
            s16x8 pf = __builtin_shufflevector(plo, phi, 0, 1, 2, 3, 4, 5, 6, 7);
#pragma unroll
            for (int dq = 0; dq < 4; ++dq) {
                int vrow = dq * 16 + l15;
                s16x8 vf = *(const s16x8*)&V[vrow][(quad ^ ((l15 >> 1) & 3)) * 8];
                o[qh][dq] = __builtin_amdgcn_mfma_f32_16x16x32_bf16(pf, vf, o[qh][dq], 0, 0, 0);
            }
        }
    };

    // ---- frag loaders -----------------------------------------------------
    auto ldK = [&](const short* kb, s16x8* kf) {  // row-major K -> QK B-frags
#pragma unroll
        for (int f = 0; f < 4; ++f) {
            int kh = f >> 1, kc = f & 1;
            kf[f] = *(const s16x8*)&kb[(kh * 16 + l15) * 64 + kc * 32 + quad * 8];
        }
    };
    auto ldV = [&](const short* vb, s16x8* vf) {  // frag-major V -> PV B-frags
#pragma unroll
        for (int dq = 0; dq < 4; ++dq)
            vf[dq] = *(const s16x8*)&vb[(dq * 64 + lane) * 8];
    };

    // ---- pipelined step: QK -> (reload K) -> exp -> PV -> (reload V) ------
    auto step = [&](s16x8* kf, s16x8* vf, float m0, float m1,
                    const short* nkb, const short* nvb,
                    float* nm0, float* nm1, int nmc) {
        f32x4 s[2][2];
        qk_mm(kf, s);
        if (nkb) {
            ldK(nkb, kf);
            *nm0 = mp[nmc * 32 + l15] * LOG2E;
            *nm1 = mp[nmc * 32 + 16 + l15] * LOG2E;
        }
        exp_p(s, m0, m1);
        pv_reg(vf);
        if (nvb) ldV(nvb, vf);
    };

    // ---- fast chunks: cache0 {4w..4w+3} (+ self on wave 0), 2-deep A/B ----
    const int c0base = w * 4;
    const short* kcb = k0p + (size_t)c0base * 2048;
    const short* vcb = v0p + (size_t)c0base * 2048;

    s16x8 kfA[4], vfA[4], kfB[4], vfB[4];
    float mA0, mA1, mB0, mB1;

    ldK(kcb, kfA);             ldV(vcb, vfA);
    mA0 = mp[c0base * 32 + l15] * LOG2E;
    mA1 = mp[c0base * 32 + 16 + l15] * LOG2E;
    ldK(kcb + 2048, kfB);      ldV(vcb + 2048, vfB);
    mB0 = mp[(c0base + 1) * 32 + l15] * LOG2E;
    mB1 = mp[(c0base + 1) * 32 + 16 + l15] * LOG2E;

    // it0: compute chunk c0base+0, prefetch c0base+2 into A
    step(kfA, vfA, mA0, mA1, kcb + 2 * 2048, vcb + 2 * 2048, &mA0, &mA1, c0base + 2);
    // it1: compute chunk c0base+1, prefetch c0base+3 into B
    step(kfB, vfB, mB0, mB1, kcb + 3 * 2048, vcb + 3 * 2048, &mB0, &mB1, c0base + 3);
    if (w == 0) {
        // it2: compute c0base+2, prefetch SELF into A
        step(kfA, vfA, mA0, mA1, kspF, vspF, &mA0, &mA1, 20);
        // it3: compute c0base+3
        step(kfB, vfB, mB0, mB1, nullptr, nullptr, nullptr, nullptr, 0);
        // it4: compute self
        step(kfA, vfA, mA0, mA1, nullptr, nullptr, nullptr, nullptr, 0);
    } else {
        step(kfA, vfA, mA0, mA1, nullptr, nullptr, nullptr, nullptr, 0);
        step(kfB, vfB, mB0, mB1, nullptr, nullptr, nullptr, nullptr, 0);
    }

    // ---- cache1 chunk (16+w): K in-reg f32->bf16 frags; V via LDS ---------
    {
        const float* sk = k1p + w * 2048;
        const float* sv = v1p + w * 2048;
        float4 vvr[8];
#pragma unroll
        for (int i = 0; i < 8; ++i)
            vvr[i] = *(const float4*)&sv[(i * 4 + skey) * 64 + sc4];
        s16x8 kc1[4];
#pragma unroll
        for (int f = 0; f < 4; ++f) {
            int kh = f >> 1, kc = f & 1;
            const float* kfp = &sk[(kh * 16 + l15) * 64 + kc * 32 + quad * 8];
            float4 lo = *(const float4*)kfp;
            float4 hi = *(const float4*)(kfp + 4);
            kc1[f] = {f2bf(lo.x), f2bf(lo.y), f2bf(lo.z), f2bf(lo.w),
                      f2bf(hi.x), f2bf(hi.y), f2bf(hi.z), f2bf(hi.w)};
        }
        int mc = 16 + w;
        float mv0 = mp[mc * 32 + l15] * LOG2E;
        float mv1 = mp[mc * 32 + 16 + l15] * LOG2E;
        f32x4 s[2][2];
        qk_mm(kc1, s);
        exp_p(s, mv0, mv1);
#pragma unroll
        for (int i = 0; i < 8; ++i) {         // scatter V f32 -> swizzled LDS
            int key = i * 4 + skey;
            int kg = key >> 3, ks = key & 7;
#pragma unroll
            for (int j = 0; j < 4; ++j) {
                int rowv = sc4 + j;
                float fv = (j == 0) ? vvr[i].x : (j == 1) ? vvr[i].y : (j == 2) ? vvr[i].z : vvr[i].w;
                V[rowv][(kg ^ ((rowv >> 1) & 3)) * 8 + ks] = f2bf(fv);
            }
        }
        pv_lds();
    }

    // ---- merge: sum 4 wave-partials (o, l) via aliased LDS scratch --------
    float lred[2][4];
#pragma unroll
    for (int qh = 0; qh < 2; ++qh)
#pragma unroll
        for (int r = 0; r < 4; ++r) {
            float l = lpart[qh][r];
            l += __shfl_xor(l, 1);
            l += __shfl_xor(l, 2);
            l += __shfl_xor(l, 4);
            l += __shfl_xor(l, 8);
            lred[qh][r] = l;
        }

    __syncthreads();                           // everyone done with V/P
#pragma unroll
    for (int qh = 0; qh < 2; ++qh)
#pragma unroll
        for (int dq = 0; dq < 4; ++dq)
#pragma unroll
            for (int r = 0; r < 4; ++r) {
                int row = qh * 16 + quad * 4 + r, col = dq * 16 + l15;
                smf[w * 2048 + row * 64 + col] = o[qh][dq][r];
            }
    if (l15 == 0) {
#pragma unroll
        for (int qh = 0; qh < 2; ++qh)
#pragma unroll
            for (int r = 0; r < 4; ++r)
                smf[8192 + w * 32 + qh * 16 + quad * 4 + r] = lred[qh][r];
    }
    __syncthreads();

    {
        int row = t >> 3, c8 = (t & 7) * 8;
        float lt = smf[8192 + row] + smf[8192 + 32 + row] +
                   smf[8192 + 64 + row] + smf[8192 + 96 + row];
        float inv = 1.f / lt;
        float4 o0, o1;
#pragma unroll
        for (int j = 0; j < 4; ++j) {
            int col = c8 + j;
            o0[j] = (smf[row * 64 + col] + smf[2048 + row * 64 + col] +
                     smf[4096 + row * 64 + col] + smf[6144 + row * 64 + col]) * inv;
        }
#pragma unroll
        for (int j = 0; j < 4; ++j) {
            int col = c8 + 4 + j;
            o1[j] = (smf[row * 64 + col] + smf[2048 + row * 64 + col] +
                     smf[4096 + row * 64 + col] + smf[6144 + row * 64 + col]) * inv;
        }
        float* op = &out[((size_t)B * SLOT_LEN + row) * HIDDEN + h * 64 + c8];
        *(float4*)op = o0;
        *(float4*)(op + 4) = o1;
    }
}

// ---------------------------------------------------------------------------
extern "C" void kernel_launch(void* const* d_in, const int* in_sizes, int n_in,
                              void* d_out, int out_size, void* d_ws, size_t ws_size,
                              hipStream_t stream) {
    const float* hs   = (const float*)d_in[0];
    const float* mask = (const float*)d_in[1];
    const float* c0k  = (const float*)d_in[2];
    const float* c0v  = (const float*)d_in[3];
    const float* c1k  = (const float*)d_in[4];
    const float* c1v  = (const float*)d_in[5];
    const float* Wq   = (const float*)d_in[6];
    const float* bq   = (const float*)d_in[7];
    const float* Wk   = (const float*)d_in[8];
    const float* bk   = (const float*)d_in[9];
    const float* Wv   = (const float*)d_in[10];
    const float* bv   = (const float*)d_in[11];
    float* out = (float*)d_out;

    short* hsb = (short*)d_ws;
    short* WtA = hsb + HS_SHORTS;
    short* qb  = WtA + WT_SHORTS;
    short* kbw = qb + QKV_SHORTS;
    short* vbw = kbw + QKV_SHORTS;

    const size_t need = (HS_SHORTS + WT_SHORTS + 3 * QKV_SHORTS + 2 * C0_SHORTS) * sizeof(short);

    if (ws_size >= need) {
        // roomy path: k0c/v0f get their own region; ALL prep in ONE launch
        // before qkv. 3 launches total.
        short* k0c = vbw + QKV_SHORTS;
        short* v0f = k0c + C0_SHORTS;
        prep_all<<<HS_BLOCKS + W_BLOCKS + C0_BLOCKS, 256, 0, stream>>>(
            hs, Wq, Wk, Wv, c0k, c0v, hsb, WtA, k0c, v0f, HS_BLOCKS, W_BLOCKS);
        qkv_mfma<<<dim3(HIDDEN / 128, M_TOK / 128, 3), 256, 0, stream>>>(
            hsb, WtA, bq, bk, bv, qb, kbw, vbw);
        attn_mfma<<<FULL * NUM_HEADS, 256, 0, stream>>>(
            qb, kbw, vbw, k0c, v0f, c1k, c1v, mask, out);
    } else {
        // fallback: k0c/v0f overlap hsb/WtA (dead after qkv); c0-prep runs
        // after qkv. 4 launches.
        short* k0c = (short*)d_ws;
        short* v0f = k0c + C0_SHORTS;
        prep_all<<<HS_BLOCKS + W_BLOCKS, 256, 0, stream>>>(
            hs, Wq, Wk, Wv, c0k, c0v, hsb, WtA, k0c, v0f, HS_BLOCKS, W_BLOCKS);
        qkv_mfma<<<dim3(HIDDEN / 128, M_TOK / 128, 3), 256, 0, stream>>>(
            hsb, WtA, bq, bk, bv, qb, kbw, vbw);
        prep_all<<<C0_BLOCKS, 256, 0, stream>>>(
            hs, Wq, Wk, Wv, c0k, c0v, hsb, WtA, k0c, v0f, 0, 0);
        attn_mfma<<<FULL * NUM_HEADS, 256, 0, stream>>>(
            qb, kbw, vbw, k0c, v0f, c1k, c1v, mask, out);
    }
}